// Round 7
// baseline (269.035 us; speedup 1.0000x reference)
//
#include <hip/hip_runtime.h>
#include <hip/hip_bf16.h>

// N=4, C=256, H=W=64 -> HW=4096, E=128, 3E=384.
// qkv flat [n][o][hw] IS [n][p][384]: q=p*384+0..127, k=+128, v=+256.
// attn flat [n][i*128+d] reinterpreted as [n][e][hw] by k_oproj (raw reshape).
// Column softmax (over i): scores s=q.k/64, |s|<~1.2 -> direct sum-exp (no max), lse=log(Z).
// k_attn reads K/V fragments DIRECTLY from global (L2): both are natural 16B row chunks.

typedef short bfrag __attribute__((ext_vector_type(8)));   // 8 bf16 (4 VGPRs)
typedef float ffrag __attribute__((ext_vector_type(4)));   // 4 fp32 acc
typedef unsigned short us4 __attribute__((ext_vector_type(4)));
#define MFMA(a,b,c) __builtin_amdgcn_mfma_f32_16x16x32_bf16((a),(b),(c),0,0,0)

__device__ __forceinline__ unsigned short f2bf(float f){
  union { float f; unsigned u; } v; v.f = f;
  unsigned r = v.u + 0x7fffu + ((v.u >> 16) & 1u);   // RNE
  return (unsigned short)(r >> 16);
}
__device__ __forceinline__ float bf2f(unsigned short h){
  union { unsigned u; float f; } v; v.u = ((unsigned)h) << 16; return v.f;
}
__device__ __forceinline__ unsigned bfpack(float a, float b){
  return (unsigned)f2bf(a) | ((unsigned)f2bf(b) << 16);
}

// ---------------- K0: cast weights to bf16 ----------------
__global__ __launch_bounds__(256) void k_wcast(const float* __restrict__ Wq, const float* __restrict__ Wo,
                                               unsigned short* __restrict__ Wqb, unsigned short* __restrict__ Wob){
  int i = blockIdx.x*256 + threadIdx.x;
  if (i < 384*256) Wqb[i] = f2bf(Wq[i]);
  if (i < 256*128) Wob[i] = f2bf(Wo[i]);
}

// ---------------- K1: QKV projection (D[m=hw][n=o] -> ushort4 stores; float4 x staging) ----------------
__global__ __launch_bounds__(256) void k_qkv(const float* __restrict__ x, const unsigned short* __restrict__ Wqb,
                                             const float* __restrict__ bq, unsigned short* __restrict__ qkv){
  constexpr int LD = 136;
  __shared__ __align__(16) unsigned short As[64*LD];   // W tile [o][c-half]
  __shared__ __align__(16) unsigned short Bs[64*LD];   // X^T tile [hw][c-half]
  const int o0 = blockIdx.x*64, h0 = blockIdx.y*64, n = blockIdx.z;
  const int t = threadIdx.x, w = t>>6, lane = t&63, lr = lane&15, q4 = lane>>4;
  ffrag acc[4] = {};
  for (int kh = 0; kh < 2; ++kh) {
    __syncthreads();
    #pragma unroll
    for (int r=0;r<4;++r){
      int pi = t + 256*r; int o = pi>>4, seg = pi&15;
      *(uint4*)&As[o*LD + seg*8] = *(const uint4*)(Wqb + (o0+o)*256 + kh*128 + seg*8);
    }
    #pragma unroll
    for (int r=0;r<8;++r){                       // 2048 = 128 c x 16 h-quads, float4 loads
      int idx = t + 256*r; int cl = idx>>4, h4 = idx&15;
      float4 v = *(const float4*)(x + (size_t)(n*256 + kh*128 + cl)*4096 + h0 + h4*4);
      Bs[(h4*4+0)*LD + cl] = f2bf(v.x);
      Bs[(h4*4+1)*LD + cl] = f2bf(v.y);
      Bs[(h4*4+2)*LD + cl] = f2bf(v.z);
      Bs[(h4*4+3)*LD + cl] = f2bf(v.w);
    }
    __syncthreads();
    #pragma unroll
    for (int kk=0;kk<4;++kk){
      bfrag a = *(const bfrag*)&Bs[(w*16+lr)*LD + kk*32 + q4*8];   // A = x^T rows (hw)
      #pragma unroll
      for (int ot=0;ot<4;++ot){
        bfrag b = *(const bfrag*)&As[(ot*16+lr)*LD + kk*32 + q4*8]; // B = W rows (o)
        acc[ot] = MFMA(a,b,acc[ot]);                                // D[m=hw][n=o]
      }
    }
  }
  size_t base = (size_t)n*384*4096;
  #pragma unroll
  for (int ot=0;ot<4;++ot){
    int o  = o0 + ot*16 + lr;
    float bias = bq[o];
    int hw = h0 + w*16 + q4*4;
    us4 pk;
    pk.x = f2bf(acc[ot][0] + bias); pk.y = f2bf(acc[ot][1] + bias);
    pk.z = f2bf(acc[ot][2] + bias); pk.w = f2bf(acc[ot][3] + bias);
    *(us4*)(qkv + base + (size_t)o*4096 + hw) = pk;
  }
}

// ---------------- K2: global V transpose: vt[n][d][p] = v[n][p][d] ----------------
__global__ __launch_bounds__(256) void k_vtrans(const unsigned short* __restrict__ qkv, unsigned short* __restrict__ vt){
  constexpr int LD = 136;
  __shared__ __align__(16) unsigned short T[64*LD];
  const int p0 = blockIdx.x*64, n = blockIdx.y;
  const int t = threadIdx.x;
  size_t base = (size_t)n*384*4096;
  #pragma unroll
  for (int r=0;r<4;++r){
    int pi = t + 256*r; int pl = pi>>4, seg = pi&15;
    *(uint4*)&T[pl*LD + seg*8] = *(const uint4*)(qkv + base + (size_t)(p0+pl)*384 + 256 + seg*8);
  }
  __syncthreads();
  unsigned* vt32 = (unsigned*)(vt + (size_t)n*128*4096);
  #pragma unroll
  for (int r=0;r<16;++r){
    int pi = t + 256*r;            // 4096 = 128 d x 32 p-pairs
    int d = pi>>5, k = pi&31;
    unsigned lo = T[(2*k)*LD + d];
    unsigned hi = T[(2*k+1)*LD + d];
    vt32[(size_t)d*2048 + (p0>>1) + k] = lo | (hi<<16);
  }
}

// ---------------- K3: column Z partials: Z_j = sum_i exp(q_i.k_j/64) (no max; bounded scores) ----------------
__global__ __launch_bounds__(256) void k_stats(const unsigned short* __restrict__ qkv,
                                               float* __restrict__ zp){
  constexpr int LD = 136;
  __shared__ __align__(16) unsigned short Qs[64*LD];   // 17408 B
  const int j0 = blockIdx.x*128, ic = blockIdx.y, n = blockIdx.z;
  const int t = threadIdx.x, w = t>>6, lane = t&63, lr = lane&15, q4 = lane>>4;
  size_t base = (size_t)n*384*4096;
  bfrag kf[2][4];
  #pragma unroll
  for (int js=0; js<2; ++js){
    const unsigned short* krow = qkv + base + (size_t)(j0 + w*32 + js*16 + lr)*384 + 128;
    #pragma unroll
    for (int kk=0;kk<4;++kk) kf[js][kk] = *(const bfrag*)(krow + kk*32 + q4*8);
  }
  float Zc[8] = {};                       // [js*4 + r]
  const float inv64 = 0.015625f;
  for (int rnd=0; rnd<8; ++rnd){          // 8 x 64-i stage rounds (ic chunk = 512 i)
    int i0 = (ic<<9) + rnd*64;
    __syncthreads();
    #pragma unroll
    for (int r=0;r<4;++r){
      int pi = t + 256*r; int il = pi>>4, seg = pi&15;
      *(uint4*)&Qs[il*LD + seg*8] = *(const uint4*)(qkv + base + (size_t)(i0+il)*384 + seg*8);
    }
    __syncthreads();
    #pragma unroll
    for (int it=0; it<4; ++it){
      bfrag qb[4];
      #pragma unroll
      for (int kk=0;kk<4;++kk) qb[kk] = *(const bfrag*)&Qs[(it*16+lr)*LD + kk*32 + q4*8];
      #pragma unroll
      for (int js=0; js<2; ++js){
        ffrag s = {};
        #pragma unroll
        for (int kk=0;kk<4;++kk) s = MFMA(kf[js][kk], qb[kk], s);   // D[m=j][n=i]
        #pragma unroll
        for (int r=0;r<4;++r) Zc[js*4+r] += __expf(s[r]*inv64);
      }
    }
  }
  #pragma unroll
  for (int v=0; v<8; ++v){
    float z = Zc[v];
    z += __shfl_xor(z, 1); z += __shfl_xor(z, 2);
    z += __shfl_xor(z, 4); z += __shfl_xor(z, 8);
    Zc[v] = z;
  }
  if (lr == 0){
    int jb = j0 + w*32;
    float* zrow = zp + (size_t)((n<<3)+ic)*4096;
    #pragma unroll
    for (int js=0; js<2; ++js)
      #pragma unroll
      for (int r=0;r<4;++r)
        zrow[jb + js*16 + q4*4 + r] = Zc[js*4+r];
  }
}

// ---------------- K4: merge partial Z -> lse[n][j] = log(sum Z) ----------------
__global__ __launch_bounds__(256) void k_merge(const float* __restrict__ zp, float* __restrict__ lse){
  int idx = blockIdx.x*256 + threadIdx.x;   // n*4096 + j
  int n = idx>>12, j = idx&4095;
  float Z = 0.f;
  #pragma unroll
  for (int c=0;c<8;++c) Z += zp[(size_t)((n<<3)+c)*4096 + j];
  lse[idx] = __logf(Z);
}

// ---------------- K5: PV pass — LDS-free K/V: fragments loaded straight from global (L2) ----------------
// Wave owns 32 i (2 Q-frag sets). QK: D[m=j][n=i]=MFMA(Kfrag,Q); K-frag = 16B chunk of qkv row (natural).
// PV: D[m=d][n=i]=MFMA(Vfrag,P); V-frag = 16B chunk of vtg row (natural). Only P round-trips via
// wave-private LDS. Zero barriers. bf16 partials, 4 j-slices (jh=4).
__global__ __launch_bounds__(256) void k_attn(const unsigned short* __restrict__ qkv,
                                              const unsigned short* __restrict__ vtg_all,
                                              const float* __restrict__ lse,
                                              unsigned short* __restrict__ part){
  constexpr int LDP = 72;
  __shared__ __align__(16) unsigned short Pw[4][32*LDP];   // per-wave P[i 0..31][j 0..63], 18432 B
  const int i0 = blockIdx.x*128, jh = blockIdx.y, n = blockIdx.z;
  const int t = threadIdx.x, w = t>>6, lane = t&63, lr = lane&15, q4 = lane>>4;
  size_t base = (size_t)n*384*4096;
  const unsigned short* vtg = vtg_all + (size_t)n*128*4096;
  const float* lsen = lse + (n<<12);
  bfrag qf[2][4];   // B[k=d][n=i] for 2 i-subtiles
  #pragma unroll
  for (int isub=0;isub<2;++isub){
    const unsigned short* qrow = qkv + base + (size_t)(i0 + w*32 + isub*16 + lr)*384;
    #pragma unroll
    for (int kk=0;kk<4;++kk) qf[isub][kk] = *(const bfrag*)(qrow + kk*32 + q4*8);
  }
  ffrag acc[8][2] = {};
  const float inv64 = 0.015625f;
  for (int j0 = jh*1024; j0 < jh*1024+1024; j0 += 64){
    #pragma unroll
    for (int jt=0;jt<4;++jt){
      const unsigned short* krow = qkv + base + (size_t)(j0 + jt*16 + lr)*384 + 128;
      bfrag kf[4];
      #pragma unroll
      for (int kk=0;kk<4;++kk) kf[kk] = *(const bfrag*)(krow + kk*32 + q4*8);  // A[m=j][k=d]
      float4 l4 = *(const float4*)(lsen + j0 + jt*16 + q4*4);
      #pragma unroll
      for (int isub=0;isub<2;++isub){
        ffrag s = {};
        #pragma unroll
        for (int kk=0;kk<4;++kk) s = MFMA(kf[kk], qf[isub][kk], s);   // D[m=j][n=i]
        float p0 = __expf(s[0]*inv64 - l4.x);
        float p1 = __expf(s[1]*inv64 - l4.y);
        float p2 = __expf(s[2]*inv64 - l4.z);
        float p3 = __expf(s[3]*inv64 - l4.w);
        uint2 pk; pk.x = bfpack(p0,p1); pk.y = bfpack(p2,p3);
        *(uint2*)&Pw[w][(isub*16+lr)*LDP + jt*16 + q4*4] = pk;   // wave-private
      }
    }
    asm volatile("" ::: "memory");             // no compiler reorder of Pw read above writes
    #pragma unroll
    for (int jk=0;jk<2;++jk){
      bfrag pf0 = *(const bfrag*)&Pw[w][lr*LDP      + jk*32 + q4*8];  // B[k=j][n=i] isub 0
      bfrag pf1 = *(const bfrag*)&Pw[w][(16+lr)*LDP + jk*32 + q4*8];  // isub 1
      #pragma unroll
      for (int dt=0;dt<8;++dt){
        bfrag af = *(const bfrag*)(vtg + (size_t)(dt*16+lr)*4096 + j0 + jk*32 + q4*8); // A[m=d][k=j]
        acc[dt][0] = MFMA(af, pf0, acc[dt][0]);   // D[m=d][n=i]
        acc[dt][1] = MFMA(af, pf1, acc[dt][1]);
      }
    }
  }
  unsigned short* po = part + (size_t)(jh*4+n)*524288;
  #pragma unroll
  for (int isub=0;isub<2;++isub){
    const int i = i0 + w*32 + isub*16 + lr;
    #pragma unroll
    for (int dt=0;dt<8;++dt){
      us4 pk;
      pk.x = f2bf(acc[dt][isub][0]); pk.y = f2bf(acc[dt][isub][1]);
      pk.z = f2bf(acc[dt][isub][2]); pk.w = f2bf(acc[dt][isub][3]);
      *(us4*)(po + (size_t)i*128 + dt*16 + q4*4) = pk;
    }
  }
}

// ---------------- K6: output projection, sums 4 bf16 partial slices, c-tile 128 ----------------
__global__ __launch_bounds__(256) void k_oproj(const unsigned short* __restrict__ part,
                                               const unsigned short* __restrict__ Wob,
                                               const float* __restrict__ bo, float* __restrict__ y){
  constexpr int LD = 136;
  __shared__ __align__(16) unsigned short As[128*LD];  // Wo tile [c][e]
  __shared__ __align__(16) unsigned short Rt[64*LD];   // attn^T [hw][e]
  const int c0 = blockIdx.x*128, h0 = blockIdx.y*64, n = blockIdx.z;
  const int t = threadIdx.x, w = t>>6, lane = t&63, lr = lane&15, q4 = lane>>4;
  #pragma unroll
  for (int r=0;r<8;++r){
    int pi = t + 256*r; int cl = pi>>4, seg = pi&15;
    *(uint4*)&As[cl*LD + seg*8] = *(const uint4*)(Wob + (c0+cl)*128 + seg*8);
  }
  #pragma unroll
  for (int r=0;r<8;++r){                     // 2048 = 128 e x 16 h-quads
    int pi = t + 256*r; int e = pi>>4, h4 = pi&15;
    size_t f = (size_t)e*4096 + h0 + h4*4;
    float a0=0.f,a1=0.f,a2=0.f,a3=0.f;
    #pragma unroll
    for (int s=0;s<4;++s){
      uint2 u = *(const uint2*)(part + (size_t)(s*4+n)*524288 + f);
      a0 += bf2f((unsigned short)(u.x & 0xffffu));
      a1 += bf2f((unsigned short)(u.x >> 16));
      a2 += bf2f((unsigned short)(u.y & 0xffffu));
      a3 += bf2f((unsigned short)(u.y >> 16));
    }
    Rt[(h4*4+0)*LD + e] = f2bf(a0);
    Rt[(h4*4+1)*LD + e] = f2bf(a1);
    Rt[(h4*4+2)*LD + e] = f2bf(a2);
    Rt[(h4*4+3)*LD + e] = f2bf(a3);
  }
  __syncthreads();
  ffrag acc[8] = {};
  #pragma unroll
  for (int kk=0;kk<4;++kk){
    bfrag a = *(const bfrag*)&Rt[(w*16+lr)*LD + kk*32 + q4*8];   // A = attn^T rows (hw)
    #pragma unroll
    for (int cs=0;cs<8;++cs){
      bfrag b = *(const bfrag*)&As[(cs*16+lr)*LD + kk*32 + q4*8]; // B = Wo rows (c)
      acc[cs] = MFMA(a,b,acc[cs]);                                // D[m=hw][n=c]
    }
  }
  #pragma unroll
  for (int cs=0;cs<8;++cs){
    int c = c0 + cs*16 + lr;
    float bias = bo[c];
    float4 v4 = { acc[cs][0]+bias, acc[cs][1]+bias, acc[cs][2]+bias, acc[cs][3]+bias };
    *(float4*)(y + ((size_t)n*256 + c)*4096 + h0 + w*16 + q4*4) = v4;
  }
}

extern "C" void kernel_launch(void* const* d_in, const int* in_sizes, int n_in,
                              void* d_out, int out_size, void* d_ws, size_t ws_size,
                              hipStream_t stream){
  const float* x  = (const float*)d_in[0];
  const float* Wq = (const float*)d_in[1];
  const float* bq = (const float*)d_in[2];
  const float* Wo = (const float*)d_in[3];
  const float* bo = (const float*)d_in[4];
  float* y = (float*)d_out;
  char* ws = (char*)d_ws;
  unsigned short* qkv  = (unsigned short*)(ws + 0);          // 12,582,912
  unsigned short* vtg  = (unsigned short*)(ws + 12582912);   //  4,194,304
  unsigned short* Wqb  = (unsigned short*)(ws + 16777216);   //    196,608
  unsigned short* Wob  = (unsigned short*)(ws + 16973824);   //     65,536
  float* zp   = (float*)(ws + 17039360);                     //    524,288 (4n x 8ic x 4096)
  float* lse  = (float*)(ws + 17563648);                     //     65,536
  unsigned short* part = (unsigned short*)(ws + 17629184);   // 16,777,216 (16 bf16 slices: jh*4+n) end ~34.4MB

  k_wcast <<<dim3(384),     256, 0, stream>>>(Wq, Wo, Wqb, Wob);
  k_qkv   <<<dim3(6,64,4),  256, 0, stream>>>(x, Wqb, bq, qkv);
  k_vtrans<<<dim3(64,4),    256, 0, stream>>>(qkv, vtg);
  k_stats <<<dim3(32,8,4),  256, 0, stream>>>(qkv, zp);
  k_merge <<<dim3(64),      256, 0, stream>>>(zp, lse);
  k_attn  <<<dim3(32,4,4),  256, 0, stream>>>(qkv, vtg, lse, part);
  k_oproj <<<dim3(2,64,4),  256, 0, stream>>>(part, Wob, bo, y);
}

// Round 8
// 186.570 us; speedup vs baseline: 1.4420x; 1.4420x over previous
//
#include <hip/hip_runtime.h>
#include <hip/hip_bf16.h>

// N=4, C=256, H=W=64 -> HW=4096, E=128, 3E=384.
// qkv flat [n][o][hw] IS [n][p][384]: q=p*384+0..127, k=+128, v=+256.
// attn flat [n][i*128+d] reinterpreted as [n][e][hw] by k_oproj (raw reshape).
// Column softmax (over i): scores s=q.k/64, |s|<~1.2 -> direct sum-exp (no max), lse=log(Z).
// k_attn/k_stats: register-level operand reuse (2 i-subtiles / 4 j-subtiles per wave)
// to cut LDS reads per MFMA below 1 (the R6 81.7us kernel was LDS-BW-bound at 1:1).

typedef short bfrag __attribute__((ext_vector_type(8)));   // 8 bf16 (4 VGPRs)
typedef float ffrag __attribute__((ext_vector_type(4)));   // 4 fp32 acc
typedef unsigned short us4 __attribute__((ext_vector_type(4)));
#define MFMA(a,b,c) __builtin_amdgcn_mfma_f32_16x16x32_bf16((a),(b),(c),0,0,0)

__device__ __forceinline__ unsigned short f2bf(float f){
  union { float f; unsigned u; } v; v.f = f;
  unsigned r = v.u + 0x7fffu + ((v.u >> 16) & 1u);   // RNE
  return (unsigned short)(r >> 16);
}
__device__ __forceinline__ float bf2f(unsigned short h){
  union { unsigned u; float f; } v; v.u = ((unsigned)h) << 16; return v.f;
}
__device__ __forceinline__ unsigned bfpack(float a, float b){
  return (unsigned)f2bf(a) | ((unsigned)f2bf(b) << 16);
}

// ---------------- K0: cast weights to bf16 ----------------
__global__ __launch_bounds__(256) void k_wcast(const float* __restrict__ Wq, const float* __restrict__ Wo,
                                               unsigned short* __restrict__ Wqb, unsigned short* __restrict__ Wob){
  int i = blockIdx.x*256 + threadIdx.x;
  if (i < 384*256) Wqb[i] = f2bf(Wq[i]);
  if (i < 256*128) Wob[i] = f2bf(Wo[i]);
}

// ---------------- K1: QKV projection (D[m=hw][n=o] -> ushort4 stores; float4 x staging) ----------------
__global__ __launch_bounds__(256) void k_qkv(const float* __restrict__ x, const unsigned short* __restrict__ Wqb,
                                             const float* __restrict__ bq, unsigned short* __restrict__ qkv){
  constexpr int LD = 136;
  __shared__ __align__(16) unsigned short As[64*LD];   // W tile [o][c-half]
  __shared__ __align__(16) unsigned short Bs[64*LD];   // X^T tile [hw][c-half]
  const int o0 = blockIdx.x*64, h0 = blockIdx.y*64, n = blockIdx.z;
  const int t = threadIdx.x, w = t>>6, lane = t&63, lr = lane&15, q4 = lane>>4;
  ffrag acc[4] = {};
  for (int kh = 0; kh < 2; ++kh) {
    __syncthreads();
    #pragma unroll
    for (int r=0;r<4;++r){
      int pi = t + 256*r; int o = pi>>4, seg = pi&15;
      *(uint4*)&As[o*LD + seg*8] = *(const uint4*)(Wqb + (o0+o)*256 + kh*128 + seg*8);
    }
    #pragma unroll
    for (int r=0;r<8;++r){                       // 2048 = 128 c x 16 h-quads, float4 loads
      int idx = t + 256*r; int cl = idx>>4, h4 = idx&15;
      float4 v = *(const float4*)(x + (size_t)(n*256 + kh*128 + cl)*4096 + h0 + h4*4);
      Bs[(h4*4+0)*LD + cl] = f2bf(v.x);
      Bs[(h4*4+1)*LD + cl] = f2bf(v.y);
      Bs[(h4*4+2)*LD + cl] = f2bf(v.z);
      Bs[(h4*4+3)*LD + cl] = f2bf(v.w);
    }
    __syncthreads();
    #pragma unroll
    for (int kk=0;kk<4;++kk){
      bfrag a = *(const bfrag*)&Bs[(w*16+lr)*LD + kk*32 + q4*8];   // A = x^T rows (hw)
      #pragma unroll
      for (int ot=0;ot<4;++ot){
        bfrag b = *(const bfrag*)&As[(ot*16+lr)*LD + kk*32 + q4*8]; // B = W rows (o)
        acc[ot] = MFMA(a,b,acc[ot]);                                // D[m=hw][n=o]
      }
    }
  }
  size_t base = (size_t)n*384*4096;
  #pragma unroll
  for (int ot=0;ot<4;++ot){
    int o  = o0 + ot*16 + lr;
    float bias = bq[o];
    int hw = h0 + w*16 + q4*4;
    us4 pk;
    pk.x = f2bf(acc[ot][0] + bias); pk.y = f2bf(acc[ot][1] + bias);
    pk.z = f2bf(acc[ot][2] + bias); pk.w = f2bf(acc[ot][3] + bias);
    *(us4*)(qkv + base + (size_t)o*4096 + hw) = pk;
  }
}

// ---------------- K2: global V transpose: vt[n][d][p] = v[n][p][d] ----------------
__global__ __launch_bounds__(256) void k_vtrans(const unsigned short* __restrict__ qkv, unsigned short* __restrict__ vt){
  constexpr int LD = 136;
  __shared__ __align__(16) unsigned short T[64*LD];
  const int p0 = blockIdx.x*64, n = blockIdx.y;
  const int t = threadIdx.x;
  size_t base = (size_t)n*384*4096;
  #pragma unroll
  for (int r=0;r<4;++r){
    int pi = t + 256*r; int pl = pi>>4, seg = pi&15;
    *(uint4*)&T[pl*LD + seg*8] = *(const uint4*)(qkv + base + (size_t)(p0+pl)*384 + 256 + seg*8);
  }
  __syncthreads();
  unsigned* vt32 = (unsigned*)(vt + (size_t)n*128*4096);
  #pragma unroll
  for (int r=0;r<16;++r){
    int pi = t + 256*r;            // 4096 = 128 d x 32 p-pairs
    int d = pi>>5, k = pi&31;
    unsigned lo = T[(2*k)*LD + d];
    unsigned hi = T[(2*k+1)*LD + d];
    vt32[(size_t)d*2048 + (p0>>1) + k] = lo | (hi<<16);
  }
}

// ---------------- K3: column Z partials, wave owns 64 j (16 reg K-frags, 4 MFMA per Q read) ----------------
__global__ __launch_bounds__(256) void k_stats(const unsigned short* __restrict__ qkv,
                                               float* __restrict__ zp){
  constexpr int LD = 136;
  __shared__ __align__(16) unsigned short Qs[64*LD];   // 17408 B
  const int j0 = blockIdx.x*256, ic = blockIdx.y, n = blockIdx.z;
  const int t = threadIdx.x, w = t>>6, lane = t&63, lr = lane&15, q4 = lane>>4;
  size_t base = (size_t)n*384*4096;
  bfrag kf[4][4];
  #pragma unroll
  for (int js=0; js<4; ++js){
    const unsigned short* krow = qkv + base + (size_t)(j0 + w*64 + js*16 + lr)*384 + 128;
    #pragma unroll
    for (int kk=0;kk<4;++kk) kf[js][kk] = *(const bfrag*)(krow + kk*32 + q4*8);
  }
  float Zc[16] = {};                      // [js*4 + r]
  const float inv64 = 0.015625f;
  for (int rnd=0; rnd<8; ++rnd){          // 8 x 64-i stage rounds (ic chunk = 512 i)
    int i0 = (ic<<9) + rnd*64;
    __syncthreads();
    #pragma unroll
    for (int r=0;r<4;++r){
      int pi = t + 256*r; int il = pi>>4, seg = pi&15;
      *(uint4*)&Qs[il*LD + seg*8] = *(const uint4*)(qkv + base + (size_t)(i0+il)*384 + seg*8);
    }
    __syncthreads();
    #pragma unroll
    for (int it=0; it<4; ++it){
      bfrag qb[4];
      #pragma unroll
      for (int kk=0;kk<4;++kk) qb[kk] = *(const bfrag*)&Qs[(it*16+lr)*LD + kk*32 + q4*8];
      #pragma unroll
      for (int js=0; js<4; ++js){
        ffrag s = {};
        #pragma unroll
        for (int kk=0;kk<4;++kk) s = MFMA(kf[js][kk], qb[kk], s);   // D[m=j][n=i]
        #pragma unroll
        for (int r=0;r<4;++r) Zc[js*4+r] += __expf(s[r]*inv64);
      }
    }
  }
  #pragma unroll
  for (int v=0; v<16; ++v){
    float z = Zc[v];
    z += __shfl_xor(z, 1); z += __shfl_xor(z, 2);
    z += __shfl_xor(z, 4); z += __shfl_xor(z, 8);
    Zc[v] = z;
  }
  if (lr == 0){
    int jb = j0 + w*64;
    float* zrow = zp + (size_t)((n<<3)+ic)*4096;
    #pragma unroll
    for (int js=0; js<4; ++js)
      #pragma unroll
      for (int r=0;r<4;++r)
        zrow[jb + js*16 + q4*4 + r] = Zc[js*4+r];
  }
}

// ---------------- K4: merge partial Z -> lse[n][j] = log(sum Z) ----------------
__global__ __launch_bounds__(256) void k_merge(const float* __restrict__ zp, float* __restrict__ lse){
  int idx = blockIdx.x*256 + threadIdx.x;   // n*4096 + j
  int n = idx>>12, j = idx&4095;
  float Z = 0.f;
  #pragma unroll
  for (int c=0;c<8;++c) Z += zp[(size_t)((n<<3)+c)*4096 + j];
  lse[idx] = __logf(Z);
}

// ---------------- K5: PV pass — R6 LDS structure + 2 i-subtiles/wave (K/V frags feed 2 MFMAs) ----------------
// QK: D[m=j][n=i] = MFMA(K,Q); P = exp(s/64 - lse_j); PV: D[m=d][n=i] = MFMA(Vt,P).
// i-tile 128 (4 waves x 32 i), j-step 64, jh=4 -> 16 iters; bf16 partials, slice jh*4+n.
__global__ __launch_bounds__(256) void k_attn(const unsigned short* __restrict__ qkv,
                                              const unsigned short* __restrict__ vtg_all,
                                              const float* __restrict__ lse,
                                              unsigned short* __restrict__ part){
  constexpr int LDK = 136, LDV = 72, LDP = 72;
  __shared__ __align__(16) unsigned short Ks[64*LDK];    // 17408 B
  __shared__ __align__(16) unsigned short Vt[128*LDV];   // 18432 B
  __shared__ __align__(16) unsigned short Pw[4][32*LDP]; // 18432 B
  __shared__ float Ls[64];
  const int i0 = blockIdx.x*128, jh = blockIdx.y, n = blockIdx.z;
  const int t = threadIdx.x, w = t>>6, lane = t&63, lr = lane&15, q4 = lane>>4;
  size_t base = (size_t)n*384*4096;
  const unsigned short* vtg = vtg_all + (size_t)n*128*4096;
  const float* lsen = lse + (n<<12);
  bfrag qf[2][4];   // B[k=d][n=i] for 2 i-subtiles (register-resident)
  #pragma unroll
  for (int isub=0;isub<2;++isub){
    const unsigned short* qrow = qkv + base + (size_t)(i0 + w*32 + isub*16 + lr)*384;
    #pragma unroll
    for (int kk=0;kk<4;++kk) qf[isub][kk] = *(const bfrag*)(qrow + kk*32 + q4*8);
  }
  ffrag acc[8][2] = {};
  const float inv64 = 0.015625f;
  for (int j0 = jh*1024; j0 < jh*1024+1024; j0 += 64){
    __syncthreads();
    #pragma unroll
    for (int r=0;r<4;++r){                    // K rows j0..j0+63
      int pi = t + 256*r; int jl = pi>>4, seg = pi&15;
      *(uint4*)&Ks[jl*LDK + seg*8] = *(const uint4*)(qkv + base + (size_t)(j0+jl)*384 + 128 + seg*8);
    }
    #pragma unroll
    for (int r=0;r<4;++r){                    // Vt[128 d][64 j]
      int pi = t + 256*r; int d = pi>>3, c = pi&7;
      *(uint4*)&Vt[d*LDV + c*8] = *(const uint4*)(vtg + (size_t)d*4096 + j0 + c*8);
    }
    if (t < 64) Ls[t] = lsen[j0 + t];
    __syncthreads();
    #pragma unroll
    for (int jt=0;jt<4;++jt){
      bfrag kf[4];
      #pragma unroll
      for (int kk=0;kk<4;++kk) kf[kk] = *(const bfrag*)&Ks[(jt*16+lr)*LDK + kk*32 + q4*8]; // A[m=j][k=d]
      float4 l4 = *(const float4*)&Ls[jt*16 + q4*4];
      #pragma unroll
      for (int isub=0;isub<2;++isub){         // each K-frag feeds 2 MFMA chains
        ffrag s = {};
        #pragma unroll
        for (int kk=0;kk<4;++kk) s = MFMA(kf[kk], qf[isub][kk], s);   // D[m=j][n=i]
        float p0 = __expf(s[0]*inv64 - l4.x);
        float p1 = __expf(s[1]*inv64 - l4.y);
        float p2 = __expf(s[2]*inv64 - l4.z);
        float p3 = __expf(s[3]*inv64 - l4.w);
        uint2 pk; pk.x = bfpack(p0,p1); pk.y = bfpack(p2,p3);
        *(uint2*)&Pw[w][(isub*16+lr)*LDP + jt*16 + q4*4] = pk;   // wave-private
      }
    }
    asm volatile("" ::: "memory");             // no compiler reorder of Pw read above writes
    #pragma unroll
    for (int jk=0;jk<2;++jk){
      bfrag pf0 = *(const bfrag*)&Pw[w][lr*LDP      + jk*32 + q4*8];  // B[k=j][n=i] isub 0
      bfrag pf1 = *(const bfrag*)&Pw[w][(16+lr)*LDP + jk*32 + q4*8];  // isub 1
      #pragma unroll
      for (int dt=0;dt<8;++dt){
        bfrag af = *(const bfrag*)&Vt[(dt*16+lr)*LDV + jk*32 + q4*8]; // A[m=d][k=j], feeds 2 MFMAs
        acc[dt][0] = MFMA(af, pf0, acc[dt][0]);   // D[m=d][n=i]
        acc[dt][1] = MFMA(af, pf1, acc[dt][1]);
      }
    }
  }
  unsigned short* po = part + (size_t)(jh*4+n)*524288;
  #pragma unroll
  for (int isub=0;isub<2;++isub){
    const int i = i0 + w*32 + isub*16 + lr;
    #pragma unroll
    for (int dt=0;dt<8;++dt){
      us4 pk;
      pk.x = f2bf(acc[dt][isub][0]); pk.y = f2bf(acc[dt][isub][1]);
      pk.z = f2bf(acc[dt][isub][2]); pk.w = f2bf(acc[dt][isub][3]);
      *(us4*)(po + (size_t)i*128 + dt*16 + q4*4) = pk;
    }
  }
}

// ---------------- K6: output projection, sums 4 bf16 partial slices, c-tile 128 ----------------
__global__ __launch_bounds__(256) void k_oproj(const unsigned short* __restrict__ part,
                                               const unsigned short* __restrict__ Wob,
                                               const float* __restrict__ bo, float* __restrict__ y){
  constexpr int LD = 136;
  __shared__ __align__(16) unsigned short As[128*LD];  // Wo tile [c][e]
  __shared__ __align__(16) unsigned short Rt[64*LD];   // attn^T [hw][e]
  const int c0 = blockIdx.x*128, h0 = blockIdx.y*64, n = blockIdx.z;
  const int t = threadIdx.x, w = t>>6, lane = t&63, lr = lane&15, q4 = lane>>4;
  #pragma unroll
  for (int r=0;r<8;++r){
    int pi = t + 256*r; int cl = pi>>4, seg = pi&15;
    *(uint4*)&As[cl*LD + seg*8] = *(const uint4*)(Wob + (c0+cl)*128 + seg*8);
  }
  #pragma unroll
  for (int r=0;r<8;++r){                     // 2048 = 128 e x 16 h-quads
    int pi = t + 256*r; int e = pi>>4, h4 = pi&15;
    size_t f = (size_t)e*4096 + h0 + h4*4;
    float a0=0.f,a1=0.f,a2=0.f,a3=0.f;
    #pragma unroll
    for (int s=0;s<4;++s){
      uint2 u = *(const uint2*)(part + (size_t)(s*4+n)*524288 + f);
      a0 += bf2f((unsigned short)(u.x & 0xffffu));
      a1 += bf2f((unsigned short)(u.x >> 16));
      a2 += bf2f((unsigned short)(u.y & 0xffffu));
      a3 += bf2f((unsigned short)(u.y >> 16));
    }
    Rt[(h4*4+0)*LD + e] = f2bf(a0);
    Rt[(h4*4+1)*LD + e] = f2bf(a1);
    Rt[(h4*4+2)*LD + e] = f2bf(a2);
    Rt[(h4*4+3)*LD + e] = f2bf(a3);
  }
  __syncthreads();
  ffrag acc[8] = {};
  #pragma unroll
  for (int kk=0;kk<4;++kk){
    bfrag a = *(const bfrag*)&Rt[(w*16+lr)*LD + kk*32 + q4*8];   // A = attn^T rows (hw)
    #pragma unroll
    for (int cs=0;cs<8;++cs){
      bfrag b = *(const bfrag*)&As[(cs*16+lr)*LD + kk*32 + q4*8]; // B = Wo rows (c)
      acc[cs] = MFMA(a,b,acc[cs]);                                // D[m=hw][n=c]
    }
  }
  #pragma unroll
  for (int cs=0;cs<8;++cs){
    int c = c0 + cs*16 + lr;
    float bias = bo[c];
    float4 v4 = { acc[cs][0]+bias, acc[cs][1]+bias, acc[cs][2]+bias, acc[cs][3]+bias };
    *(float4*)(y + ((size_t)n*256 + c)*4096 + h0 + w*16 + q4*4) = v4;
  }
}

extern "C" void kernel_launch(void* const* d_in, const int* in_sizes, int n_in,
                              void* d_out, int out_size, void* d_ws, size_t ws_size,
                              hipStream_t stream){
  const float* x  = (const float*)d_in[0];
  const float* Wq = (const float*)d_in[1];
  const float* bq = (const float*)d_in[2];
  const float* Wo = (const float*)d_in[3];
  const float* bo = (const float*)d_in[4];
  float* y = (float*)d_out;
  char* ws = (char*)d_ws;
  unsigned short* qkv  = (unsigned short*)(ws + 0);          // 12,582,912
  unsigned short* vtg  = (unsigned short*)(ws + 12582912);   //  4,194,304
  unsigned short* Wqb  = (unsigned short*)(ws + 16777216);   //    196,608
  unsigned short* Wob  = (unsigned short*)(ws + 16973824);   //     65,536
  float* zp   = (float*)(ws + 17039360);                     //    524,288 (4n x 8ic x 4096)
  float* lse  = (float*)(ws + 17563648);                     //     65,536
  unsigned short* part = (unsigned short*)(ws + 17629184);   // 16,777,216 (16 bf16 slices jh*4+n) end ~34.4MB

  k_wcast <<<dim3(384),     256, 0, stream>>>(Wq, Wo, Wqb, Wob);
  k_qkv   <<<dim3(6,64,4),  256, 0, stream>>>(x, Wqb, bq, qkv);
  k_vtrans<<<dim3(64,4),    256, 0, stream>>>(qkv, vtg);
  k_stats <<<dim3(16,8,4),  256, 0, stream>>>(qkv, zp);
  k_merge <<<dim3(64),      256, 0, stream>>>(zp, lse);
  k_attn  <<<dim3(32,4,4),  256, 0, stream>>>(qkv, vtg, lse, part);
  k_oproj <<<dim3(2,64,4),  256, 0, stream>>>(part, Wob, bo, y);
}

// Round 9
// 181.505 us; speedup vs baseline: 1.4822x; 1.0279x over previous
//
#include <hip/hip_runtime.h>
#include <hip/hip_bf16.h>

// N=4, C=256, H=W=64 -> HW=4096, E=128, 3E=384.
// qkv flat [n][o][hw] IS [n][p][384]: q=p*384+0..127, k=+128, v=+256.
// attn flat [n][i*128+d] reinterpreted as [n][e][hw] by k_oproj (raw reshape).
// Column softmax (over i): scores s=q.k/64, |s|<~1.2 -> direct sum-exp (no max), lse=log(Z).

typedef short bfrag __attribute__((ext_vector_type(8)));   // 8 bf16 (4 VGPRs)
typedef float ffrag __attribute__((ext_vector_type(4)));   // 4 fp32 acc
typedef unsigned short us4 __attribute__((ext_vector_type(4)));
#define MFMA(a,b,c) __builtin_amdgcn_mfma_f32_16x16x32_bf16((a),(b),(c),0,0,0)

__device__ __forceinline__ unsigned short f2bf(float f){
  union { float f; unsigned u; } v; v.f = f;
  unsigned r = v.u + 0x7fffu + ((v.u >> 16) & 1u);   // RNE
  return (unsigned short)(r >> 16);
}
__device__ __forceinline__ float bf2f(unsigned short h){
  union { unsigned u; float f; } v; v.u = ((unsigned)h) << 16; return v.f;
}
__device__ __forceinline__ unsigned bfpack(float a, float b){
  return (unsigned)f2bf(a) | ((unsigned)f2bf(b) << 16);
}

// ---------------- K0: cast weights to bf16 ----------------
__global__ __launch_bounds__(256) void k_wcast(const float* __restrict__ Wq, const float* __restrict__ Wo,
                                               unsigned short* __restrict__ Wqb, unsigned short* __restrict__ Wob){
  int i = blockIdx.x*256 + threadIdx.x;
  if (i < 384*256) Wqb[i] = f2bf(Wq[i]);
  if (i < 256*128) Wob[i] = f2bf(Wo[i]);
}

// ---------------- K1: QKV projection, o-tile 128 (x re-read 3x instead of 6x) ----------------
__global__ __launch_bounds__(256) void k_qkv(const float* __restrict__ x, const unsigned short* __restrict__ Wqb,
                                             const float* __restrict__ bq, unsigned short* __restrict__ qkv){
  constexpr int LD = 136;
  __shared__ __align__(16) unsigned short As[128*LD];  // W tile [o 128][c-half 128]  34816 B
  __shared__ __align__(16) unsigned short Bs[64*LD];   // X^T tile [hw 64][c-half]    17408 B
  const int o0 = blockIdx.x*128, h0 = blockIdx.y*64, n = blockIdx.z;
  const int t = threadIdx.x, w = t>>6, lane = t&63, lr = lane&15, q4 = lane>>4;
  ffrag acc[8] = {};
  for (int kh = 0; kh < 2; ++kh) {
    __syncthreads();
    #pragma unroll
    for (int r=0;r<8;++r){                       // 2048 = 128 o x 16 segs
      int pi = t + 256*r; int o = pi>>4, seg = pi&15;
      *(uint4*)&As[o*LD + seg*8] = *(const uint4*)(Wqb + (o0+o)*256 + kh*128 + seg*8);
    }
    #pragma unroll
    for (int r=0;r<8;++r){                       // 2048 = 128 c x 16 h-quads, float4 loads
      int idx = t + 256*r; int cl = idx>>4, h4 = idx&15;
      float4 v = *(const float4*)(x + (size_t)(n*256 + kh*128 + cl)*4096 + h0 + h4*4);
      Bs[(h4*4+0)*LD + cl] = f2bf(v.x);
      Bs[(h4*4+1)*LD + cl] = f2bf(v.y);
      Bs[(h4*4+2)*LD + cl] = f2bf(v.z);
      Bs[(h4*4+3)*LD + cl] = f2bf(v.w);
    }
    __syncthreads();
    #pragma unroll
    for (int kk=0;kk<4;++kk){
      bfrag a = *(const bfrag*)&Bs[(w*16+lr)*LD + kk*32 + q4*8];   // A = x^T rows (hw)
      #pragma unroll
      for (int ot=0;ot<8;++ot){
        bfrag b = *(const bfrag*)&As[(ot*16+lr)*LD + kk*32 + q4*8]; // B = W rows (o)
        acc[ot] = MFMA(a,b,acc[ot]);                                // D[m=hw][n=o]
      }
    }
  }
  size_t base = (size_t)n*384*4096;
  #pragma unroll
  for (int ot=0;ot<8;++ot){
    int o  = o0 + ot*16 + lr;
    float bias = bq[o];
    int hw = h0 + w*16 + q4*4;
    us4 pk;
    pk.x = f2bf(acc[ot][0] + bias); pk.y = f2bf(acc[ot][1] + bias);
    pk.z = f2bf(acc[ot][2] + bias); pk.w = f2bf(acc[ot][3] + bias);
    *(us4*)(qkv + base + (size_t)o*4096 + hw) = pk;
  }
}

// ---------------- K2: column Z partials, wave owns 64 j (16 reg K-frags, 4 MFMA per Q read) ----------------
__global__ __launch_bounds__(256) void k_stats(const unsigned short* __restrict__ qkv,
                                               float* __restrict__ zp){
  constexpr int LD = 136;
  __shared__ __align__(16) unsigned short Qs[64*LD];   // 17408 B
  const int j0 = blockIdx.x*256, ic = blockIdx.y, n = blockIdx.z;
  const int t = threadIdx.x, w = t>>6, lane = t&63, lr = lane&15, q4 = lane>>4;
  size_t base = (size_t)n*384*4096;
  bfrag kf[4][4];
  #pragma unroll
  for (int js=0; js<4; ++js){
    const unsigned short* krow = qkv + base + (size_t)(j0 + w*64 + js*16 + lr)*384 + 128;
    #pragma unroll
    for (int kk=0;kk<4;++kk) kf[js][kk] = *(const bfrag*)(krow + kk*32 + q4*8);
  }
  float Zc[16] = {};                      // [js*4 + r]
  const float inv64 = 0.015625f;
  for (int rnd=0; rnd<8; ++rnd){          // 8 x 64-i stage rounds (ic chunk = 512 i)
    int i0 = (ic<<9) + rnd*64;
    __syncthreads();
    #pragma unroll
    for (int r=0;r<4;++r){
      int pi = t + 256*r; int il = pi>>4, seg = pi&15;
      *(uint4*)&Qs[il*LD + seg*8] = *(const uint4*)(qkv + base + (size_t)(i0+il)*384 + seg*8);
    }
    __syncthreads();
    #pragma unroll
    for (int it=0; it<4; ++it){
      bfrag qb[4];
      #pragma unroll
      for (int kk=0;kk<4;++kk) qb[kk] = *(const bfrag*)&Qs[(it*16+lr)*LD + kk*32 + q4*8];
      #pragma unroll
      for (int js=0; js<4; ++js){
        ffrag s = {};
        #pragma unroll
        for (int kk=0;kk<4;++kk) s = MFMA(kf[js][kk], qb[kk], s);   // D[m=j][n=i]
        #pragma unroll
        for (int r=0;r<4;++r) Zc[js*4+r] += __expf(s[r]*inv64);
      }
    }
  }
  #pragma unroll
  for (int v=0; v<16; ++v){
    float z = Zc[v];
    z += __shfl_xor(z, 1); z += __shfl_xor(z, 2);
    z += __shfl_xor(z, 4); z += __shfl_xor(z, 8);
    Zc[v] = z;
  }
  if (lr == 0){
    int jb = j0 + w*64;
    float* zrow = zp + (size_t)((n<<3)+ic)*4096;
    #pragma unroll
    for (int js=0; js<4; ++js)
      #pragma unroll
      for (int r=0;r<4;++r)
        zrow[jb + js*16 + q4*4 + r] = Zc[js*4+r];
  }
}

// ---------------- K3: V transpose + fused lse merge: vt[n][d][p]=v[n][p][d]; lse[n][j]=log(sum zp) ----------------
__global__ __launch_bounds__(256) void k_vtrans(const unsigned short* __restrict__ qkv,
                                                const float* __restrict__ zp,
                                                unsigned short* __restrict__ vt,
                                                float* __restrict__ lse){
  constexpr int LD = 136;
  __shared__ __align__(16) unsigned short T[64*LD];
  const int p0 = blockIdx.x*64, n = blockIdx.y;
  const int t = threadIdx.x;
  size_t base = (size_t)n*384*4096;
  #pragma unroll
  for (int r=0;r<4;++r){
    int pi = t + 256*r; int pl = pi>>4, seg = pi&15;
    *(uint4*)&T[pl*LD + seg*8] = *(const uint4*)(qkv + base + (size_t)(p0+pl)*384 + 256 + seg*8);
  }
  if (t < 64){                            // fused k_merge for this block's 64 j
    float Z = 0.f;
    #pragma unroll
    for (int c=0;c<8;++c) Z += zp[(size_t)((n<<3)+c)*4096 + p0 + t];
    lse[(n<<12) + p0 + t] = __logf(Z);
  }
  __syncthreads();
  unsigned* vt32 = (unsigned*)(vt + (size_t)n*128*4096);
  #pragma unroll
  for (int r=0;r<16;++r){
    int pi = t + 256*r;            // 4096 = 128 d x 32 p-pairs
    int d = pi>>5, k = pi&31;
    unsigned lo = T[(2*k)*LD + d];
    unsigned hi = T[(2*k+1)*LD + d];
    vt32[(size_t)d*2048 + (p0>>1) + k] = lo | (hi<<16);
  }
}

// ---------------- K4: PV pass — byte-identical to R8 (measured 57.5 us) ----------------
__global__ __launch_bounds__(256) void k_attn(const unsigned short* __restrict__ qkv,
                                              const unsigned short* __restrict__ vtg_all,
                                              const float* __restrict__ lse,
                                              unsigned short* __restrict__ part){
  constexpr int LDK = 136, LDV = 72, LDP = 72;
  __shared__ __align__(16) unsigned short Ks[64*LDK];    // 17408 B
  __shared__ __align__(16) unsigned short Vt[128*LDV];   // 18432 B
  __shared__ __align__(16) unsigned short Pw[4][32*LDP]; // 18432 B
  __shared__ float Ls[64];
  const int i0 = blockIdx.x*128, jh = blockIdx.y, n = blockIdx.z;
  const int t = threadIdx.x, w = t>>6, lane = t&63, lr = lane&15, q4 = lane>>4;
  size_t base = (size_t)n*384*4096;
  const unsigned short* vtg = vtg_all + (size_t)n*128*4096;
  const float* lsen = lse + (n<<12);
  bfrag qf[2][4];   // B[k=d][n=i] for 2 i-subtiles (register-resident)
  #pragma unroll
  for (int isub=0;isub<2;++isub){
    const unsigned short* qrow = qkv + base + (size_t)(i0 + w*32 + isub*16 + lr)*384;
    #pragma unroll
    for (int kk=0;kk<4;++kk) qf[isub][kk] = *(const bfrag*)(qrow + kk*32 + q4*8);
  }
  ffrag acc[8][2] = {};
  const float inv64 = 0.015625f;
  for (int j0 = jh*1024; j0 < jh*1024+1024; j0 += 64){
    __syncthreads();
    #pragma unroll
    for (int r=0;r<4;++r){                    // K rows j0..j0+63
      int pi = t + 256*r; int jl = pi>>4, seg = pi&15;
      *(uint4*)&Ks[jl*LDK + seg*8] = *(const uint4*)(qkv + base + (size_t)(j0+jl)*384 + 128 + seg*8);
    }
    #pragma unroll
    for (int r=0;r<4;++r){                    // Vt[128 d][64 j]
      int pi = t + 256*r; int d = pi>>3, c = pi&7;
      *(uint4*)&Vt[d*LDV + c*8] = *(const uint4*)(vtg + (size_t)d*4096 + j0 + c*8);
    }
    if (t < 64) Ls[t] = lsen[j0 + t];
    __syncthreads();
    #pragma unroll
    for (int jt=0;jt<4;++jt){
      bfrag kf[4];
      #pragma unroll
      for (int kk=0;kk<4;++kk) kf[kk] = *(const bfrag*)&Ks[(jt*16+lr)*LDK + kk*32 + q4*8]; // A[m=j][k=d]
      float4 l4 = *(const float4*)&Ls[jt*16 + q4*4];
      #pragma unroll
      for (int isub=0;isub<2;++isub){         // each K-frag feeds 2 MFMA chains
        ffrag s = {};
        #pragma unroll
        for (int kk=0;kk<4;++kk) s = MFMA(kf[kk], qf[isub][kk], s);   // D[m=j][n=i]
        float p0 = __expf(s[0]*inv64 - l4.x);
        float p1 = __expf(s[1]*inv64 - l4.y);
        float p2 = __expf(s[2]*inv64 - l4.z);
        float p3 = __expf(s[3]*inv64 - l4.w);
        uint2 pk; pk.x = bfpack(p0,p1); pk.y = bfpack(p2,p3);
        *(uint2*)&Pw[w][(isub*16+lr)*LDP + jt*16 + q4*4] = pk;   // wave-private
      }
    }
    asm volatile("" ::: "memory");             // no compiler reorder of Pw read above writes
    #pragma unroll
    for (int jk=0;jk<2;++jk){
      bfrag pf0 = *(const bfrag*)&Pw[w][lr*LDP      + jk*32 + q4*8];  // B[k=j][n=i] isub 0
      bfrag pf1 = *(const bfrag*)&Pw[w][(16+lr)*LDP + jk*32 + q4*8];  // isub 1
      #pragma unroll
      for (int dt=0;dt<8;++dt){
        bfrag af = *(const bfrag*)&Vt[(dt*16+lr)*LDV + jk*32 + q4*8]; // A[m=d][k=j], feeds 2 MFMAs
        acc[dt][0] = MFMA(af, pf0, acc[dt][0]);   // D[m=d][n=i]
        acc[dt][1] = MFMA(af, pf1, acc[dt][1]);
      }
    }
  }
  unsigned short* po = part + (size_t)(jh*4+n)*524288;
  #pragma unroll
  for (int isub=0;isub<2;++isub){
    const int i = i0 + w*32 + isub*16 + lr;
    #pragma unroll
    for (int dt=0;dt<8;++dt){
      us4 pk;
      pk.x = f2bf(acc[dt][isub][0]); pk.y = f2bf(acc[dt][isub][1]);
      pk.z = f2bf(acc[dt][isub][2]); pk.w = f2bf(acc[dt][isub][3]);
      *(us4*)(po + (size_t)i*128 + dt*16 + q4*4) = pk;
    }
  }
}

// ---------------- K5: output projection, sums 4 bf16 partial slices (uint4 loads), c-tile 128 ----------------
__global__ __launch_bounds__(256) void k_oproj(const unsigned short* __restrict__ part,
                                               const unsigned short* __restrict__ Wob,
                                               const float* __restrict__ bo, float* __restrict__ y){
  constexpr int LD = 136;
  __shared__ __align__(16) unsigned short As[128*LD];  // Wo tile [c][e]
  __shared__ __align__(16) unsigned short Rt[64*LD];   // attn^T [hw][e]
  const int c0 = blockIdx.x*128, h0 = blockIdx.y*64, n = blockIdx.z;
  const int t = threadIdx.x, w = t>>6, lane = t&63, lr = lane&15, q4 = lane>>4;
  #pragma unroll
  for (int r=0;r<8;++r){
    int pi = t + 256*r; int cl = pi>>4, seg = pi&15;
    *(uint4*)&As[cl*LD + seg*8] = *(const uint4*)(Wob + (c0+cl)*128 + seg*8);
  }
  #pragma unroll
  for (int r=0;r<4;++r){                     // 1024 = 128 e x 8 h-octets, uint4 loads
    int pi = t + 256*r; int e = pi>>3, h8 = pi&7;
    size_t f = (size_t)e*4096 + h0 + h8*8;
    float a[8] = {};
    #pragma unroll
    for (int s=0;s<4;++s){
      uint4 u = *(const uint4*)(part + (size_t)(s*4+n)*524288 + f);
      a[0] += bf2f((unsigned short)(u.x & 0xffffu)); a[1] += bf2f((unsigned short)(u.x >> 16));
      a[2] += bf2f((unsigned short)(u.y & 0xffffu)); a[3] += bf2f((unsigned short)(u.y >> 16));
      a[4] += bf2f((unsigned short)(u.z & 0xffffu)); a[5] += bf2f((unsigned short)(u.z >> 16));
      a[6] += bf2f((unsigned short)(u.w & 0xffffu)); a[7] += bf2f((unsigned short)(u.w >> 16));
    }
    #pragma unroll
    for (int k=0;k<8;++k) Rt[(h8*8+k)*LD + e] = f2bf(a[k]);
  }
  __syncthreads();
  ffrag acc[8] = {};
  #pragma unroll
  for (int kk=0;kk<4;++kk){
    bfrag a = *(const bfrag*)&Rt[(w*16+lr)*LD + kk*32 + q4*8];   // A = attn^T rows (hw)
    #pragma unroll
    for (int cs=0;cs<8;++cs){
      bfrag b = *(const bfrag*)&As[(cs*16+lr)*LD + kk*32 + q4*8]; // B = Wo rows (c)
      acc[cs] = MFMA(a,b,acc[cs]);                                // D[m=hw][n=c]
    }
  }
  #pragma unroll
  for (int cs=0;cs<8;++cs){
    int c = c0 + cs*16 + lr;
    float bias = bo[c];
    float4 v4 = { acc[cs][0]+bias, acc[cs][1]+bias, acc[cs][2]+bias, acc[cs][3]+bias };
    *(float4*)(y + ((size_t)n*256 + c)*4096 + h0 + w*16 + q4*4) = v4;
  }
}

extern "C" void kernel_launch(void* const* d_in, const int* in_sizes, int n_in,
                              void* d_out, int out_size, void* d_ws, size_t ws_size,
                              hipStream_t stream){
  const float* x  = (const float*)d_in[0];
  const float* Wq = (const float*)d_in[1];
  const float* bq = (const float*)d_in[2];
  const float* Wo = (const float*)d_in[3];
  const float* bo = (const float*)d_in[4];
  float* y = (float*)d_out;
  char* ws = (char*)d_ws;
  unsigned short* qkv  = (unsigned short*)(ws + 0);          // 12,582,912
  unsigned short* vtg  = (unsigned short*)(ws + 12582912);   //  4,194,304
  unsigned short* Wqb  = (unsigned short*)(ws + 16777216);   //    196,608
  unsigned short* Wob  = (unsigned short*)(ws + 16973824);   //     65,536
  float* zp   = (float*)(ws + 17039360);                     //    524,288 (4n x 8ic x 4096)
  float* lse  = (float*)(ws + 17563648);                     //     65,536
  unsigned short* part = (unsigned short*)(ws + 17629184);   // 16,777,216 (16 bf16 slices jh*4+n) end ~34.4MB

  k_wcast <<<dim3(384),     256, 0, stream>>>(Wq, Wo, Wqb, Wob);
  k_qkv   <<<dim3(3,64,4),  256, 0, stream>>>(x, Wqb, bq, qkv);
  k_stats <<<dim3(16,8,4),  256, 0, stream>>>(qkv, zp);
  k_vtrans<<<dim3(64,4),    256, 0, stream>>>(qkv, zp, vtg, lse);
  k_attn  <<<dim3(32,4,4),  256, 0, stream>>>(qkv, vtg, lse, part);
  k_oproj <<<dim3(2,64,4),  256, 0, stream>>>(part, Wob, bo, y);
}